// Round 20
// baseline (104.180 us; speedup 1.0000x reference)
//
#include <hip/hip_runtime.h>

typedef __attribute__((ext_vector_type(8))) short short8;
typedef __attribute__((ext_vector_type(4))) float f32x4;

#define N_NODES 100000
#define N_EDGES 1600000
#define IN_F 128
#define OUT_ALL 64   // HEADS*OUT_F
#define HEADS 4
#define OUT_F 16
#define NTILES (N_NODES / 16)          // 6250
#define BIN_BLOCKS 250
#define EPB (N_EDGES / BIN_BLOCKS)     // 6400 edges per bin block
#define TOTAL_BLOCKS 2048
#define PROJ_BLOCKS (TOTAL_BLOCKS - BIN_BLOCKS)   // 1798
#define SLICE_SHIFT 8
#define SLICE_NODES 256
#define NSLICES ((N_NODES + SLICE_NODES - 1) / SLICE_NODES)   // 391
#define SEG_CAP 4608                   // avg 4096 + 8 sigma
#define QUARTER_NODES 64
#define SORT_CAP 1280                  // quarter: avg 1024 + 8 sigma
#define NCHUNKS (NSLICES * 4)          // 1564
#define AGG_BLOCKS 1024                // exactly residency capacity (4/CU)

static __device__ __forceinline__ ushort f2bf(float f) {
    unsigned u = __float_as_uint(f);
    return (ushort)((u + 0x7FFF + ((u >> 16) & 1)) >> 16);   // RN, no NaN inputs
}
static __device__ __forceinline__ float bf2f(ushort b) {
    return __uint_as_float(((unsigned)b) << 16);
}
static __device__ __forceinline__ float lrelu(float v) {
    return v > 0.f ? v : 0.01f * v;
}
static __device__ __forceinline__ short8 pack_bf16x8(float4 f0, float4 f1) {
    union { unsigned u[4]; short8 s; } r;
    asm("v_cvt_pk_bf16_f32 %0, %1, %2" : "=v"(r.u[0]) : "v"(f0.x), "v"(f0.y));
    asm("v_cvt_pk_bf16_f32 %0, %1, %2" : "=v"(r.u[1]) : "v"(f0.z), "v"(f0.w));
    asm("v_cvt_pk_bf16_f32 %0, %1, %2" : "=v"(r.u[2]) : "v"(f1.x), "v"(f1.y));
    asm("v_cvt_pk_bf16_f32 %0, %1, %2" : "=v"(r.u[3]) : "v"(f1.z), "v"(f1.w));
    return r.s;
}

// ---- Kernel 0: fold att into W + zero scursor + zero work counter --------
__global__ __launch_bounds__(256) void prep_kernel(
    const float* __restrict__ W, const float* __restrict__ att_i,
    const float* __restrict__ att_j, float* __restrict__ wiwj,
    int* __restrict__ scursor, int* __restrict__ workctr)
{
    int idx = blockIdx.x * 256 + threadIdx.x;
    if (idx < NSLICES) scursor[idx] = 0;
    if (idx == NSLICES) *workctr = 0;
    if (idx >= IN_F * 8) return;
    int k = idx >> 3, c = idx & 7;
    int h = c & 3;
    const float* att = (c < 4) ? att_i : att_j;
    float s = 0.f;
    #pragma unroll
    for (int f = 0; f < 16; ++f)
        s += W[(size_t)(h * 16 + f) * IN_F + k] * att[h * OUT_F + f];
    wiwj[k * 8 + c] = s;
}

// ---- Kernel 1: fused MFMA projection (bf16-LDS x, prefetched) + binning --
// Proj: register-prefetch tile t+1 right after publishing tile t to LDS —
// the HBM round-trip overlaps MFMA+stores instead of serializing (T14).
// Bin: byte-identical to R19.
__global__ __launch_bounds__(256) void proj_bin_kernel(
    const float* __restrict__ x, const float* __restrict__ W,
    const float* __restrict__ wiwj, const int* __restrict__ ei,
    ushort* __restrict__ hb, float* __restrict__ ai, float* __restrict__ aj,
    int* __restrict__ scursor, int2* __restrict__ seg)
{
    __shared__ int cnt[NSLICES];              // 1.6 KB
    __shared__ int gbase[NSLICES];            // 1.6 KB
    __shared__ int run[NSLICES];              // 1.6 KB
    __shared__ __align__(16) ushort xsb[16][144];  // bf16 tile, 288B pitch, 4.6 KB

    if (blockIdx.x < BIN_BLOCKS) {
        int base = blockIdx.x * EPB;
        const int4* __restrict__ srcp = (const int4*)(ei + base);
        const int4* __restrict__ dstp = (const int4*)(ei + N_EDGES + base);
        for (int s = threadIdx.x; s < NSLICES; s += 256) { cnt[s] = 0; run[s] = 0; }
        __syncthreads();
        for (int i = threadIdx.x; i < EPB / 4; i += 256) {
            int4 d = dstp[i];
            atomicAdd(&cnt[d.x >> SLICE_SHIFT], 1);
            atomicAdd(&cnt[d.y >> SLICE_SHIFT], 1);
            atomicAdd(&cnt[d.z >> SLICE_SHIFT], 1);
            atomicAdd(&cnt[d.w >> SLICE_SHIFT], 1);
        }
        __syncthreads();
        for (int s = threadIdx.x; s < NSLICES; s += 256) {
            int c = cnt[s];
            gbase[s] = c ? atomicAdd(&scursor[s], c) : 0;
        }
        __syncthreads();
        for (int i = threadIdx.x; i < EPB / 4; i += 256) {
            int4 sv = srcp[i];
            int4 dv = dstp[i];
            int ss, p;
            ss = dv.x >> SLICE_SHIFT; p = gbase[ss] + atomicAdd(&run[ss], 1);
            if (p < SEG_CAP) seg[(size_t)ss * SEG_CAP + p] = make_int2(sv.x, dv.x);
            ss = dv.y >> SLICE_SHIFT; p = gbase[ss] + atomicAdd(&run[ss], 1);
            if (p < SEG_CAP) seg[(size_t)ss * SEG_CAP + p] = make_int2(sv.y, dv.y);
            ss = dv.z >> SLICE_SHIFT; p = gbase[ss] + atomicAdd(&run[ss], 1);
            if (p < SEG_CAP) seg[(size_t)ss * SEG_CAP + p] = make_int2(sv.z, dv.z);
            ss = dv.w >> SLICE_SHIFT; p = gbase[ss] + atomicAdd(&run[ss], 1);
            if (p < SEG_CAP) seg[(size_t)ss * SEG_CAP + p] = make_int2(sv.w, dv.w);
        }
        return;
    }

    int bproj = blockIdx.x - BIN_BLOCKS;       // 0..1797
    const int nproj = PROJ_BLOCKS;

    int w   = threadIdx.x >> 6;    // wave id == head == 16-col n-tile
    int l   = threadIdx.x & 63;
    int col = l & 15;
    int kg  = l >> 4;              // k-group 0..3 (8 k each)

    short8 bw[4];
    #pragma unroll
    for (int m = 0; m < 4; ++m) {
        const float* wp = W + (size_t)(w * 16 + col) * IN_F + m * 32 + kg * 8;
        float4 f0 = *(const float4*)wp;
        float4 f1 = *(const float4*)(wp + 4);
        bw[m] = pack_bf16x8(f0, f1);
    }
    short8 bwd[4];
    #pragma unroll
    for (int m = 0; m < 4; ++m) {
        float v[8];
        #pragma unroll
        for (int j = 0; j < 8; ++j)
            v[j] = (col < 8) ? wiwj[(size_t)(m * 32 + kg * 8 + j) * 8 + col] : 0.f;
        bwd[m] = pack_bf16x8(float4{v[0], v[1], v[2], v[3]},
                             float4{v[4], v[5], v[6], v[7]});
    }

    int srow = threadIdx.x >> 4;
    int sc8  = threadIdx.x & 15;

    // prefetch first tile into registers
    float4 p0 = {0,0,0,0}, p1 = {0,0,0,0};
    if (bproj < NTILES) {
        const float* xp = x + (size_t)(bproj * 16 + srow) * IN_F + sc8 * 8;
        p0 = *(const float4*)xp;
        p1 = *(const float4*)(xp + 4);
    }

    for (int t = bproj; t < NTILES; t += nproj) {
        int nodeBase = t * 16;

        __syncthreads();   // previous tile's readers done
        *(short8*)&xsb[srow][sc8 * 8] = pack_bf16x8(p0, p1);
        __syncthreads();   // tile published

        short8 a[4];
        #pragma unroll
        for (int m = 0; m < 4; ++m)
            a[m] = *(const short8*)&xsb[col][m * 32 + kg * 8];

        // prefetch next tile (no dependency on a[] -> overlaps MFMA+stores)
        int tn = t + nproj;
        if (tn < NTILES) {
            const float* xp = x + (size_t)(tn * 16 + srow) * IN_F + sc8 * 8;
            p0 = *(const float4*)xp;
            p1 = *(const float4*)(xp + 4);
        }

        f32x4 acc = {0.f, 0.f, 0.f, 0.f};
        f32x4 accd = {0.f, 0.f, 0.f, 0.f};
        #pragma unroll
        for (int m = 0; m < 4; ++m) {
            acc  = __builtin_amdgcn_mfma_f32_16x16x32_bf16(a[m], bw[m],  acc,  0, 0, 0);
            accd = __builtin_amdgcn_mfma_f32_16x16x32_bf16(a[m], bwd[m], accd, 0, 0, 0);
        }

        #pragma unroll
        for (int r = 0; r < 4; ++r)
            hb[(size_t)(nodeBase + kg * 4 + r) * OUT_ALL + w * 16 + col] = f2bf(acc[r]);

        if (col < 4) {
            #pragma unroll
            for (int r = 0; r < 4; ++r)
                ai[(size_t)(nodeBase + kg * 4 + r) * HEADS + col] = accd[r];
        } else if (col < 8) {
            #pragma unroll
            for (int r = 0; r < 4; ++r)
                aj[(size_t)(nodeBase + kg * 4 + r) * HEADS + (col - 4)] = accd[r];
        }
    }
}

// ---- Kernel 2: persistent-block work-queue agg ---------------------------
// 1024 blocks (= residency capacity) dynamically grab 64-node chunks via a
// global counter until the 1564-chunk queue drains — no scheduling
// generations, no static imbalance (R18 lesson). Per-chunk body = R19's
// fused single-pass sort + unroll-4 register gather, unchanged.
__global__ __launch_bounds__(512) void agg_kernel(
    const int2* __restrict__ seg, const int* __restrict__ scursor,
    const ushort* __restrict__ hb, const float* __restrict__ ai,
    const float* __restrict__ aj, float* __restrict__ out,
    int* __restrict__ workctr)
{
    __shared__ int staged[SORT_CAP];          // 5.1 KB, (src<<6)|dlocal
    __shared__ int sorted_src[SORT_CAP];      // 5.1 KB
    __shared__ int cnt[QUARTER_NODES];
    __shared__ int run[QUARTER_NODES];
    __shared__ int rowptr[QUARTER_NODES + 1];
    __shared__ int scnt_s;
    __shared__ int chunk_s;

    int lane = threadIdx.x & 63;

    for (;;) {
        if (threadIdx.x == 0) chunk_s = atomicAdd(workctr, 1);
        __syncthreads();
        int chunk = chunk_s;
        if (chunk >= NCHUNKS) return;

        int s       = chunk >> 2;
        int quarter = chunk & 3;
        int nbase   = (s << SLICE_SHIFT) + quarter * QUARTER_NODES;
        int total = scursor[s]; if (total > SEG_CAP) total = SEG_CAP;
        const int2* sp = seg + (size_t)s * SEG_CAP;

        for (int i = threadIdx.x; i < QUARTER_NODES; i += 512) { cnt[i] = 0; run[i] = 0; }
        if (threadIdx.x == 0) scnt_s = 0;
        __syncthreads();

        // single pass: stage matching edges into LDS + histogram
        for (int i = threadIdx.x; i < total; i += 512) {
            int2 e = sp[i];
            int d = e.y & (SLICE_NODES - 1);
            bool m = (d >> 6) == quarter;
            unsigned long long mask = __ballot(m);
            if (mask) {
                int leader = (int)__ffsll((long long)mask) - 1;
                int base = 0;
                if (lane == leader)
                    base = atomicAdd(&scnt_s, (int)__popcll(mask));
                base = __shfl(base, leader, 64);
                if (m) {
                    int p = base + (int)__popcll(mask & ((1ull << lane) - 1ull));
                    if (p < SORT_CAP) staged[p] = (e.x << 6) | (d & 63);
                    atomicAdd(&cnt[d & 63], 1);
                }
            }
        }
        __syncthreads();

        if (threadIdx.x < 64) {
            int l = threadIdx.x;
            int v = cnt[l];
            int inc = v;
            #pragma unroll
            for (int d = 1; d < 64; d <<= 1) {
                int t = __shfl_up(inc, d, 64);
                if (l >= d) inc += t;
            }
            rowptr[l] = inc - v;
            if (l == 63) rowptr[64] = inc;
        }
        __syncthreads();

        int scnt = scnt_s; if (scnt > SORT_CAP) scnt = SORT_CAP;
        for (int i = threadIdx.x; i < scnt; i += 512) {
            int v = staged[i];
            int lb = v & 63;
            int p = rowptr[lb] + atomicAdd(&run[lb], 1);
            if (p < SORT_CAP) sorted_src[p] = (int)((unsigned)v >> 6);
        }
        __syncthreads();

        int g    = threadIdx.x >> 3;   // 0..63 == local node
        int sub  = threadIdx.x & 7;    // 8 lanes, 8 cols each
        int head = sub >> 1;
        int node = nbase + g;
        if (node < N_NODES) {
            int beg = rowptr[g], end = rowptr[g + 1];
            if (end > SORT_CAP) end = SORT_CAP;
            float aiv = ai[(size_t)node * HEADS + head];
            float acc[8] = {0.f, 0.f, 0.f, 0.f, 0.f, 0.f, 0.f, 0.f};
            float den = 0.f;

            int k = beg;
            for (; k + 4 <= end; k += 4) {
                int s0 = sorted_src[k + 0];
                int s1 = sorted_src[k + 1];
                int s2 = sorted_src[k + 2];
                int s3 = sorted_src[k + 3];
                float aj0 = aj[(size_t)s0 * HEADS + head];
                float aj1 = aj[(size_t)s1 * HEADS + head];
                float aj2 = aj[(size_t)s2 * HEADS + head];
                float aj3 = aj[(size_t)s3 * HEADS + head];
                short8 h0 = *(const short8*)(hb + (size_t)s0 * OUT_ALL + sub * 8);
                short8 h1 = *(const short8*)(hb + (size_t)s1 * OUT_ALL + sub * 8);
                short8 h2 = *(const short8*)(hb + (size_t)s2 * OUT_ALL + sub * 8);
                short8 h3 = *(const short8*)(hb + (size_t)s3 * OUT_ALL + sub * 8);
                float e0 = __expf(lrelu(aiv + aj0));
                float e1 = __expf(lrelu(aiv + aj1));
                float e2 = __expf(lrelu(aiv + aj2));
                float e3 = __expf(lrelu(aiv + aj3));
                den += (e0 + e1) + (e2 + e3);
                #pragma unroll
                for (int q = 0; q < 8; ++q)
                    acc[q] += e0 * bf2f((ushort)h0[q]) + e1 * bf2f((ushort)h1[q]) +
                              e2 * bf2f((ushort)h2[q]) + e3 * bf2f((ushort)h3[q]);
            }
            for (; k < end; ++k) {
                int src = sorted_src[k];
                float ex = __expf(lrelu(aiv + aj[(size_t)src * HEADS + head]));
                den += ex;
                short8 hv = *(const short8*)(hb + (size_t)src * OUT_ALL + sub * 8);
                #pragma unroll
                for (int q = 0; q < 8; ++q)
                    acc[q] += ex * bf2f((ushort)hv[q]);
            }

            float inv = 1.0f / (den + 1e-16f);
            float4 o0 = {acc[0] * inv, acc[1] * inv, acc[2] * inv, acc[3] * inv};
            float4 o1 = {acc[4] * inv, acc[5] * inv, acc[6] * inv, acc[7] * inv};
            float* op = out + (size_t)node * OUT_ALL + sub * 8;
            *(float4*)op = o0;
            *(float4*)(op + 4) = o1;
        }
        __syncthreads();   // all LDS consumers done before next chunk grab
    }
}

extern "C" void kernel_launch(void* const* d_in, const int* in_sizes, int n_in,
                              void* d_out, int out_size, void* d_ws, size_t ws_size,
                              hipStream_t stream) {
    const float* x     = (const float*)d_in[0];
    const int*   ei    = (const int*)d_in[1];
    const float* W     = (const float*)d_in[2];
    const float* att_i = (const float*)d_in[3];
    const float* att_j = (const float*)d_in[4];
    float* out = (float*)d_out;

    char* ws = (char*)d_ws;
    size_t off = 0;
    auto alloc = [&](size_t bytes) {
        void* p = ws + off;
        off += (bytes + 255) & ~(size_t)255;
        return p;
    };
    ushort* hb      = (ushort*)alloc((size_t)N_NODES * OUT_ALL * 2);   // 12.8 MB
    float*  ai      = (float*)alloc((size_t)N_NODES * HEADS * 4);      // 1.6 MB
    float*  aj      = (float*)alloc((size_t)N_NODES * HEADS * 4);      // 1.6 MB
    float*  wiwj    = (float*)alloc((size_t)IN_F * 8 * 4);             // 4 KB
    int*    scursor = (int*)alloc((size_t)(NSLICES + 64) * 4);         // +workctr
    int*    workctr = scursor + NSLICES;
    int2*   seg     = (int2*)alloc((size_t)NSLICES * SEG_CAP * 8);     // 14.4 MB

    prep_kernel<<<(IN_F * 8 + 255) / 256, 256, 0, stream>>>(
        W, att_i, att_j, wiwj, scursor, workctr);
    proj_bin_kernel<<<TOTAL_BLOCKS, 256, 0, stream>>>(
        x, W, wiwj, ei, hb, ai, aj, scursor, seg);
    agg_kernel<<<AGG_BLOCKS, 512, 0, stream>>>(
        seg, scursor, hb, ai, aj, out, workctr);
}

// Round 21
// 89.386 us; speedup vs baseline: 1.1655x; 1.1655x over previous
//
#include <hip/hip_runtime.h>

typedef __attribute__((ext_vector_type(8))) short short8;
typedef __attribute__((ext_vector_type(4))) float f32x4;

#define N_NODES 100000
#define N_EDGES 1600000
#define IN_F 128
#define OUT_ALL 64   // HEADS*OUT_F
#define HEADS 4
#define OUT_F 16
#define NTILES (N_NODES / 16)          // 6250
#define BIN_BLOCKS 250
#define EPB (N_EDGES / BIN_BLOCKS)     // 6400 edges per bin block
#define TOTAL_BLOCKS 2048
#define PROJ_BLOCKS (TOTAL_BLOCKS - BIN_BLOCKS)   // 1798
#define SLICE_SHIFT 8
#define SLICE_NODES 256
#define NSLICES ((N_NODES + SLICE_NODES - 1) / SLICE_NODES)   // 391
#define SEG_CAP 4608                   // avg 4096 + 8 sigma
#define QUARTER_NODES 64
#define SORT_CAP 1280                  // quarter: avg 1024 + 8 sigma

static __device__ __forceinline__ ushort f2bf(float f) {
    unsigned u = __float_as_uint(f);
    return (ushort)((u + 0x7FFF + ((u >> 16) & 1)) >> 16);   // RN, no NaN inputs
}
static __device__ __forceinline__ float bf2f(ushort b) {
    return __uint_as_float(((unsigned)b) << 16);
}
static __device__ __forceinline__ float lrelu(float v) {
    return v > 0.f ? v : 0.01f * v;
}
static __device__ __forceinline__ short8 pack_bf16x8(float4 f0, float4 f1) {
    union { unsigned u[4]; short8 s; } r;
    asm("v_cvt_pk_bf16_f32 %0, %1, %2" : "=v"(r.u[0]) : "v"(f0.x), "v"(f0.y));
    asm("v_cvt_pk_bf16_f32 %0, %1, %2" : "=v"(r.u[1]) : "v"(f0.z), "v"(f0.w));
    asm("v_cvt_pk_bf16_f32 %0, %1, %2" : "=v"(r.u[2]) : "v"(f1.x), "v"(f1.y));
    asm("v_cvt_pk_bf16_f32 %0, %1, %2" : "=v"(r.u[3]) : "v"(f1.z), "v"(f1.w));
    return r.s;
}

// ---- Kernel 0: fold att into W + zero scursor ----------------------------
__global__ __launch_bounds__(256) void prep_kernel(
    const float* __restrict__ W, const float* __restrict__ att_i,
    const float* __restrict__ att_j, float* __restrict__ wiwj,
    int* __restrict__ scursor)
{
    int idx = blockIdx.x * 256 + threadIdx.x;
    if (idx < NSLICES) scursor[idx] = 0;
    if (idx >= IN_F * 8) return;
    int k = idx >> 3, c = idx & 7;
    int h = c & 3;
    const float* att = (c < 4) ? att_i : att_j;
    float s = 0.f;
    #pragma unroll
    for (int f = 0; f < 16; ++f)
        s += W[(size_t)(h * 16 + f) * IN_F + k] * att[h * OUT_F + f];
    wiwj[k * 8 + c] = s;
}

// ---- Kernel 1: fused MFMA projection (bf16-LDS x, prefetched) + binning --
// Proj: register-prefetch of tile t+1 between LDS publish and MFMA (T14) —
// the ONLY change vs R19; hides the per-tile HBM round-trip under compute.
// Bin: byte-identical to R19.
__global__ __launch_bounds__(256) void proj_bin_kernel(
    const float* __restrict__ x, const float* __restrict__ W,
    const float* __restrict__ wiwj, const int* __restrict__ ei,
    ushort* __restrict__ hb, float* __restrict__ ai, float* __restrict__ aj,
    int* __restrict__ scursor, int2* __restrict__ seg)
{
    __shared__ int cnt[NSLICES];              // 1.6 KB
    __shared__ int gbase[NSLICES];            // 1.6 KB
    __shared__ int run[NSLICES];              // 1.6 KB
    __shared__ __align__(16) ushort xsb[16][144];  // bf16 tile, 288B pitch, 4.6 KB

    if (blockIdx.x < BIN_BLOCKS) {
        int base = blockIdx.x * EPB;
        const int4* __restrict__ srcp = (const int4*)(ei + base);
        const int4* __restrict__ dstp = (const int4*)(ei + N_EDGES + base);
        for (int s = threadIdx.x; s < NSLICES; s += 256) { cnt[s] = 0; run[s] = 0; }
        __syncthreads();
        for (int i = threadIdx.x; i < EPB / 4; i += 256) {
            int4 d = dstp[i];
            atomicAdd(&cnt[d.x >> SLICE_SHIFT], 1);
            atomicAdd(&cnt[d.y >> SLICE_SHIFT], 1);
            atomicAdd(&cnt[d.z >> SLICE_SHIFT], 1);
            atomicAdd(&cnt[d.w >> SLICE_SHIFT], 1);
        }
        __syncthreads();
        for (int s = threadIdx.x; s < NSLICES; s += 256) {
            int c = cnt[s];
            gbase[s] = c ? atomicAdd(&scursor[s], c) : 0;
        }
        __syncthreads();
        for (int i = threadIdx.x; i < EPB / 4; i += 256) {
            int4 sv = srcp[i];
            int4 dv = dstp[i];
            int ss, p;
            ss = dv.x >> SLICE_SHIFT; p = gbase[ss] + atomicAdd(&run[ss], 1);
            if (p < SEG_CAP) seg[(size_t)ss * SEG_CAP + p] = make_int2(sv.x, dv.x);
            ss = dv.y >> SLICE_SHIFT; p = gbase[ss] + atomicAdd(&run[ss], 1);
            if (p < SEG_CAP) seg[(size_t)ss * SEG_CAP + p] = make_int2(sv.y, dv.y);
            ss = dv.z >> SLICE_SHIFT; p = gbase[ss] + atomicAdd(&run[ss], 1);
            if (p < SEG_CAP) seg[(size_t)ss * SEG_CAP + p] = make_int2(sv.z, dv.z);
            ss = dv.w >> SLICE_SHIFT; p = gbase[ss] + atomicAdd(&run[ss], 1);
            if (p < SEG_CAP) seg[(size_t)ss * SEG_CAP + p] = make_int2(sv.w, dv.w);
        }
        return;
    }

    int bproj = blockIdx.x - BIN_BLOCKS;       // 0..1797
    const int nproj = PROJ_BLOCKS;

    int w   = threadIdx.x >> 6;    // wave id == head == 16-col n-tile
    int l   = threadIdx.x & 63;
    int col = l & 15;
    int kg  = l >> 4;              // k-group 0..3 (8 k each)

    short8 bw[4];
    #pragma unroll
    for (int m = 0; m < 4; ++m) {
        const float* wp = W + (size_t)(w * 16 + col) * IN_F + m * 32 + kg * 8;
        float4 f0 = *(const float4*)wp;
        float4 f1 = *(const float4*)(wp + 4);
        bw[m] = pack_bf16x8(f0, f1);
    }
    short8 bwd[4];
    #pragma unroll
    for (int m = 0; m < 4; ++m) {
        float v[8];
        #pragma unroll
        for (int j = 0; j < 8; ++j)
            v[j] = (col < 8) ? wiwj[(size_t)(m * 32 + kg * 8 + j) * 8 + col] : 0.f;
        bwd[m] = pack_bf16x8(float4{v[0], v[1], v[2], v[3]},
                             float4{v[4], v[5], v[6], v[7]});
    }

    int srow = threadIdx.x >> 4;
    int sc8  = threadIdx.x & 15;

    // prefetch first tile into registers
    float4 p0 = {0,0,0,0}, p1 = {0,0,0,0};
    if (bproj < NTILES) {
        const float* xp = x + (size_t)(bproj * 16 + srow) * IN_F + sc8 * 8;
        p0 = *(const float4*)xp;
        p1 = *(const float4*)(xp + 4);
    }

    for (int t = bproj; t < NTILES; t += nproj) {
        int nodeBase = t * 16;

        __syncthreads();   // previous tile's readers done
        *(short8*)&xsb[srow][sc8 * 8] = pack_bf16x8(p0, p1);
        __syncthreads();   // tile published

        short8 a[4];
        #pragma unroll
        for (int m = 0; m < 4; ++m)
            a[m] = *(const short8*)&xsb[col][m * 32 + kg * 8];

        // prefetch next tile (independent of a[] -> overlaps MFMA+stores)
        int tn = t + nproj;
        if (tn < NTILES) {
            const float* xp = x + (size_t)(tn * 16 + srow) * IN_F + sc8 * 8;
            p0 = *(const float4*)xp;
            p1 = *(const float4*)(xp + 4);
        }

        f32x4 acc = {0.f, 0.f, 0.f, 0.f};
        f32x4 accd = {0.f, 0.f, 0.f, 0.f};
        #pragma unroll
        for (int m = 0; m < 4; ++m) {
            acc  = __builtin_amdgcn_mfma_f32_16x16x32_bf16(a[m], bw[m],  acc,  0, 0, 0);
            accd = __builtin_amdgcn_mfma_f32_16x16x32_bf16(a[m], bwd[m], accd, 0, 0, 0);
        }

        #pragma unroll
        for (int r = 0; r < 4; ++r)
            hb[(size_t)(nodeBase + kg * 4 + r) * OUT_ALL + w * 16 + col] = f2bf(acc[r]);

        if (col < 4) {
            #pragma unroll
            for (int r = 0; r < 4; ++r)
                ai[(size_t)(nodeBase + kg * 4 + r) * HEADS + col] = accd[r];
        } else if (col < 8) {
            #pragma unroll
            for (int r = 0; r < 4; ++r)
                aj[(size_t)(nodeBase + kg * 4 + r) * HEADS + (col - 4)] = accd[r];
        }
    }
}

// ---- Kernel 2: quarter-slice sort + register gather (R19, byte-identical)-
// 1564 blocks, 1 chunk each — hardware dispatcher provides the dynamic
// load balancing (R18/R20 lessons: both static balancing and software
// work-queues lose to simple oversubscription).
__global__ __launch_bounds__(512) void agg_kernel(
    const int2* __restrict__ seg, const int* __restrict__ scursor,
    const ushort* __restrict__ hb, const float* __restrict__ ai,
    const float* __restrict__ aj, float* __restrict__ out)
{
    __shared__ int staged[SORT_CAP];          // 5.1 KB, (src<<6)|dlocal
    __shared__ int sorted_src[SORT_CAP];      // 5.1 KB
    __shared__ int cnt[QUARTER_NODES];
    __shared__ int run[QUARTER_NODES];
    __shared__ int rowptr[QUARTER_NODES + 1];
    __shared__ int scnt_s;

    int s       = blockIdx.x >> 2;
    int quarter = blockIdx.x & 3;
    int nbase   = (s << SLICE_SHIFT) + quarter * QUARTER_NODES;
    int total = scursor[s]; if (total > SEG_CAP) total = SEG_CAP;
    const int2* sp = seg + (size_t)s * SEG_CAP;

    for (int i = threadIdx.x; i < QUARTER_NODES; i += 512) { cnt[i] = 0; run[i] = 0; }
    if (threadIdx.x == 0) scnt_s = 0;
    __syncthreads();

    // single pass: stage matching edges into LDS + histogram
    int lane = threadIdx.x & 63;
    for (int i = threadIdx.x; i < total; i += 512) {
        int2 e = sp[i];
        int d = e.y & (SLICE_NODES - 1);
        bool m = (d >> 6) == quarter;
        unsigned long long mask = __ballot(m);
        if (mask) {
            int leader = (int)__ffsll((long long)mask) - 1;
            int base = 0;
            if (lane == leader)
                base = atomicAdd(&scnt_s, (int)__popcll(mask));
            base = __shfl(base, leader, 64);
            if (m) {
                int p = base + (int)__popcll(mask & ((1ull << lane) - 1ull));
                if (p < SORT_CAP) staged[p] = (e.x << 6) | (d & 63);
                atomicAdd(&cnt[d & 63], 1);
            }
        }
    }
    __syncthreads();

    // exclusive scan of 64 bins by wave 0
    if (threadIdx.x < 64) {
        int l = threadIdx.x;
        int v = cnt[l];
        int inc = v;
        #pragma unroll
        for (int d = 1; d < 64; d <<= 1) {
            int t = __shfl_up(inc, d, 64);
            if (l >= d) inc += t;
        }
        rowptr[l] = inc - v;
        if (l == 63) rowptr[64] = inc;
    }
    __syncthreads();

    // scatter from LDS staged -> sorted order
    int scnt = scnt_s; if (scnt > SORT_CAP) scnt = SORT_CAP;
    for (int i = threadIdx.x; i < scnt; i += 512) {
        int v = staged[i];
        int lb = v & 63;
        int p = rowptr[lb] + atomicAdd(&run[lb], 1);
        if (p < SORT_CAP) sorted_src[p] = (int)((unsigned)v >> 6);
    }
    __syncthreads();

    int g    = threadIdx.x >> 3;   // 0..63 == local node
    int sub  = threadIdx.x & 7;    // 8 lanes, 8 cols each
    int head = sub >> 1;
    int node = nbase + g;
    if (node >= N_NODES) return;
    int beg = rowptr[g], end = rowptr[g + 1];
    if (end > SORT_CAP) end = SORT_CAP;
    float aiv = ai[(size_t)node * HEADS + head];
    float acc[8] = {0.f, 0.f, 0.f, 0.f, 0.f, 0.f, 0.f, 0.f};
    float den = 0.f;

    int k = beg;
    for (; k + 4 <= end; k += 4) {
        int s0 = sorted_src[k + 0];
        int s1 = sorted_src[k + 1];
        int s2 = sorted_src[k + 2];
        int s3 = sorted_src[k + 3];
        float aj0 = aj[(size_t)s0 * HEADS + head];
        float aj1 = aj[(size_t)s1 * HEADS + head];
        float aj2 = aj[(size_t)s2 * HEADS + head];
        float aj3 = aj[(size_t)s3 * HEADS + head];
        short8 h0 = *(const short8*)(hb + (size_t)s0 * OUT_ALL + sub * 8);
        short8 h1 = *(const short8*)(hb + (size_t)s1 * OUT_ALL + sub * 8);
        short8 h2 = *(const short8*)(hb + (size_t)s2 * OUT_ALL + sub * 8);
        short8 h3 = *(const short8*)(hb + (size_t)s3 * OUT_ALL + sub * 8);
        float e0 = __expf(lrelu(aiv + aj0));
        float e1 = __expf(lrelu(aiv + aj1));
        float e2 = __expf(lrelu(aiv + aj2));
        float e3 = __expf(lrelu(aiv + aj3));
        den += (e0 + e1) + (e2 + e3);
        #pragma unroll
        for (int q = 0; q < 8; ++q)
            acc[q] += e0 * bf2f((ushort)h0[q]) + e1 * bf2f((ushort)h1[q]) +
                      e2 * bf2f((ushort)h2[q]) + e3 * bf2f((ushort)h3[q]);
    }
    for (; k < end; ++k) {
        int src = sorted_src[k];
        float ex = __expf(lrelu(aiv + aj[(size_t)src * HEADS + head]));
        den += ex;
        short8 hv = *(const short8*)(hb + (size_t)src * OUT_ALL + sub * 8);
        #pragma unroll
        for (int q = 0; q < 8; ++q)
            acc[q] += ex * bf2f((ushort)hv[q]);
    }

    float inv = 1.0f / (den + 1e-16f);
    float4 o0 = {acc[0] * inv, acc[1] * inv, acc[2] * inv, acc[3] * inv};
    float4 o1 = {acc[4] * inv, acc[5] * inv, acc[6] * inv, acc[7] * inv};
    float* op = out + (size_t)node * OUT_ALL + sub * 8;
    *(float4*)op = o0;
    *(float4*)(op + 4) = o1;
}

extern "C" void kernel_launch(void* const* d_in, const int* in_sizes, int n_in,
                              void* d_out, int out_size, void* d_ws, size_t ws_size,
                              hipStream_t stream) {
    const float* x     = (const float*)d_in[0];
    const int*   ei    = (const int*)d_in[1];
    const float* W     = (const float*)d_in[2];
    const float* att_i = (const float*)d_in[3];
    const float* att_j = (const float*)d_in[4];
    float* out = (float*)d_out;

    char* ws = (char*)d_ws;
    size_t off = 0;
    auto alloc = [&](size_t bytes) {
        void* p = ws + off;
        off += (bytes + 255) & ~(size_t)255;
        return p;
    };
    ushort* hb      = (ushort*)alloc((size_t)N_NODES * OUT_ALL * 2);   // 12.8 MB
    float*  ai      = (float*)alloc((size_t)N_NODES * HEADS * 4);      // 1.6 MB
    float*  aj      = (float*)alloc((size_t)N_NODES * HEADS * 4);      // 1.6 MB
    float*  wiwj    = (float*)alloc((size_t)IN_F * 8 * 4);             // 4 KB
    int*    scursor = (int*)alloc((size_t)NSLICES * 4);                // 1.6 KB
    int2*   seg     = (int2*)alloc((size_t)NSLICES * SEG_CAP * 8);     // 14.4 MB

    prep_kernel<<<(IN_F * 8 + 255) / 256, 256, 0, stream>>>(
        W, att_i, att_j, wiwj, scursor);
    proj_bin_kernel<<<TOTAL_BLOCKS, 256, 0, stream>>>(
        x, W, wiwj, ei, hb, ai, aj, scursor, seg);
    agg_kernel<<<NSLICES * 4, 512, 0, stream>>>(seg, scursor, hb, ai, aj, out);
}

// Round 22
// 86.462 us; speedup vs baseline: 1.2049x; 1.0338x over previous
//
#include <hip/hip_runtime.h>

typedef __attribute__((ext_vector_type(8))) short short8;
typedef __attribute__((ext_vector_type(4))) float f32x4;

#define N_NODES 100000
#define N_EDGES 1600000
#define IN_F 128
#define OUT_ALL 64   // HEADS*OUT_F
#define HEADS 4
#define OUT_F 16
#define NTILES (N_NODES / 16)          // 6250
#define BIN_BLOCKS 250
#define EPB (N_EDGES / BIN_BLOCKS)     // 6400 edges per bin block
#define TOTAL_BLOCKS 2048
#define PROJ_BLOCKS (TOTAL_BLOCKS - BIN_BLOCKS)   // 1798
#define SLICE_SHIFT 8
#define SLICE_NODES 256
#define NSLICES ((N_NODES + SLICE_NODES - 1) / SLICE_NODES)   // 391
#define SEG_CAP 4608                   // avg 4096 + 8 sigma
#define QUARTER_NODES 64
#define SORT_CAP 1280                  // quarter: avg 1024 + 8 sigma
#define AGG_GRID 1568                  // 8 XCD groups x 196 (s>=391 exits)

static __device__ __forceinline__ ushort f2bf(float f) {
    unsigned u = __float_as_uint(f);
    return (ushort)((u + 0x7FFF + ((u >> 16) & 1)) >> 16);   // RN, no NaN inputs
}
static __device__ __forceinline__ float bf2f(ushort b) {
    return __uint_as_float(((unsigned)b) << 16);
}
static __device__ __forceinline__ float lrelu(float v) {
    return v > 0.f ? v : 0.01f * v;
}
static __device__ __forceinline__ short8 pack_bf16x8(float4 f0, float4 f1) {
    union { unsigned u[4]; short8 s; } r;
    asm("v_cvt_pk_bf16_f32 %0, %1, %2" : "=v"(r.u[0]) : "v"(f0.x), "v"(f0.y));
    asm("v_cvt_pk_bf16_f32 %0, %1, %2" : "=v"(r.u[1]) : "v"(f0.z), "v"(f0.w));
    asm("v_cvt_pk_bf16_f32 %0, %1, %2" : "=v"(r.u[2]) : "v"(f1.x), "v"(f1.y));
    asm("v_cvt_pk_bf16_f32 %0, %1, %2" : "=v"(r.u[3]) : "v"(f1.z), "v"(f1.w));
    return r.s;
}

// ---- Kernel 0: fold att into W + zero scursor ----------------------------
__global__ __launch_bounds__(256) void prep_kernel(
    const float* __restrict__ W, const float* __restrict__ att_i,
    const float* __restrict__ att_j, float* __restrict__ wiwj,
    int* __restrict__ scursor)
{
    int idx = blockIdx.x * 256 + threadIdx.x;
    if (idx < NSLICES) scursor[idx] = 0;
    if (idx >= IN_F * 8) return;
    int k = idx >> 3, c = idx & 7;
    int h = c & 3;
    const float* att = (c < 4) ? att_i : att_j;
    float s = 0.f;
    #pragma unroll
    for (int f = 0; f < 16; ++f)
        s += W[(size_t)(h * 16 + f) * IN_F + k] * att[h * OUT_F + f];
    wiwj[k * 8 + c] = s;
}

// ---- Kernel 1: fused MFMA projection + slice binning (4B packed seg) -----
// Proj: R21 (bf16-LDS staged x + register prefetch). Bin: seg entries now
// (src<<8)|(dst&255) — 4B instead of 8B halves the scattered store bytes.
__global__ __launch_bounds__(256) void proj_bin_kernel(
    const float* __restrict__ x, const float* __restrict__ W,
    const float* __restrict__ wiwj, const int* __restrict__ ei,
    ushort* __restrict__ hb, float* __restrict__ ai, float* __restrict__ aj,
    int* __restrict__ scursor, int* __restrict__ seg)
{
    __shared__ int cnt[NSLICES];              // 1.6 KB
    __shared__ int gbase[NSLICES];            // 1.6 KB
    __shared__ int run[NSLICES];              // 1.6 KB
    __shared__ __align__(16) ushort xsb[16][144];  // bf16 tile, 288B pitch, 4.6 KB

    if (blockIdx.x < BIN_BLOCKS) {
        int base = blockIdx.x * EPB;
        const int4* __restrict__ srcp = (const int4*)(ei + base);
        const int4* __restrict__ dstp = (const int4*)(ei + N_EDGES + base);
        for (int s = threadIdx.x; s < NSLICES; s += 256) { cnt[s] = 0; run[s] = 0; }
        __syncthreads();
        for (int i = threadIdx.x; i < EPB / 4; i += 256) {
            int4 d = dstp[i];
            atomicAdd(&cnt[d.x >> SLICE_SHIFT], 1);
            atomicAdd(&cnt[d.y >> SLICE_SHIFT], 1);
            atomicAdd(&cnt[d.z >> SLICE_SHIFT], 1);
            atomicAdd(&cnt[d.w >> SLICE_SHIFT], 1);
        }
        __syncthreads();
        for (int s = threadIdx.x; s < NSLICES; s += 256) {
            int c = cnt[s];
            gbase[s] = c ? atomicAdd(&scursor[s], c) : 0;
        }
        __syncthreads();
        for (int i = threadIdx.x; i < EPB / 4; i += 256) {
            int4 sv = srcp[i];
            int4 dv = dstp[i];
            int ss, p;
            ss = dv.x >> SLICE_SHIFT; p = gbase[ss] + atomicAdd(&run[ss], 1);
            if (p < SEG_CAP) seg[(size_t)ss * SEG_CAP + p] = (sv.x << 8) | (dv.x & 255);
            ss = dv.y >> SLICE_SHIFT; p = gbase[ss] + atomicAdd(&run[ss], 1);
            if (p < SEG_CAP) seg[(size_t)ss * SEG_CAP + p] = (sv.y << 8) | (dv.y & 255);
            ss = dv.z >> SLICE_SHIFT; p = gbase[ss] + atomicAdd(&run[ss], 1);
            if (p < SEG_CAP) seg[(size_t)ss * SEG_CAP + p] = (sv.z << 8) | (dv.z & 255);
            ss = dv.w >> SLICE_SHIFT; p = gbase[ss] + atomicAdd(&run[ss], 1);
            if (p < SEG_CAP) seg[(size_t)ss * SEG_CAP + p] = (sv.w << 8) | (dv.w & 255);
        }
        return;
    }

    int bproj = blockIdx.x - BIN_BLOCKS;       // 0..1797
    const int nproj = PROJ_BLOCKS;

    int w   = threadIdx.x >> 6;    // wave id == head == 16-col n-tile
    int l   = threadIdx.x & 63;
    int col = l & 15;
    int kg  = l >> 4;              // k-group 0..3 (8 k each)

    short8 bw[4];
    #pragma unroll
    for (int m = 0; m < 4; ++m) {
        const float* wp = W + (size_t)(w * 16 + col) * IN_F + m * 32 + kg * 8;
        float4 f0 = *(const float4*)wp;
        float4 f1 = *(const float4*)(wp + 4);
        bw[m] = pack_bf16x8(f0, f1);
    }
    short8 bwd[4];
    #pragma unroll
    for (int m = 0; m < 4; ++m) {
        float v[8];
        #pragma unroll
        for (int j = 0; j < 8; ++j)
            v[j] = (col < 8) ? wiwj[(size_t)(m * 32 + kg * 8 + j) * 8 + col] : 0.f;
        bwd[m] = pack_bf16x8(float4{v[0], v[1], v[2], v[3]},
                             float4{v[4], v[5], v[6], v[7]});
    }

    int srow = threadIdx.x >> 4;
    int sc8  = threadIdx.x & 15;

    float4 p0 = {0,0,0,0}, p1 = {0,0,0,0};
    if (bproj < NTILES) {
        const float* xp = x + (size_t)(bproj * 16 + srow) * IN_F + sc8 * 8;
        p0 = *(const float4*)xp;
        p1 = *(const float4*)(xp + 4);
    }

    for (int t = bproj; t < NTILES; t += nproj) {
        int nodeBase = t * 16;

        __syncthreads();
        *(short8*)&xsb[srow][sc8 * 8] = pack_bf16x8(p0, p1);
        __syncthreads();

        short8 a[4];
        #pragma unroll
        for (int m = 0; m < 4; ++m)
            a[m] = *(const short8*)&xsb[col][m * 32 + kg * 8];

        int tn = t + nproj;
        if (tn < NTILES) {
            const float* xp = x + (size_t)(tn * 16 + srow) * IN_F + sc8 * 8;
            p0 = *(const float4*)xp;
            p1 = *(const float4*)(xp + 4);
        }

        f32x4 acc = {0.f, 0.f, 0.f, 0.f};
        f32x4 accd = {0.f, 0.f, 0.f, 0.f};
        #pragma unroll
        for (int m = 0; m < 4; ++m) {
            acc  = __builtin_amdgcn_mfma_f32_16x16x32_bf16(a[m], bw[m],  acc,  0, 0, 0);
            accd = __builtin_amdgcn_mfma_f32_16x16x32_bf16(a[m], bwd[m], accd, 0, 0, 0);
        }

        #pragma unroll
        for (int r = 0; r < 4; ++r)
            hb[(size_t)(nodeBase + kg * 4 + r) * OUT_ALL + w * 16 + col] = f2bf(acc[r]);

        if (col < 4) {
            #pragma unroll
            for (int r = 0; r < 4; ++r)
                ai[(size_t)(nodeBase + kg * 4 + r) * HEADS + col] = accd[r];
        } else if (col < 8) {
            #pragma unroll
            for (int r = 0; r < 4; ++r)
                aj[(size_t)(nodeBase + kg * 4 + r) * HEADS + (col - 4)] = accd[r];
        }
    }
}

// ---- Kernel 2: XCD-pinned quarter-slice sort + register gather -----------
// Mapping: xcd=b&7, j=b>>3, s=xcd+8*(j>>2), q=j&3 — the 4 quarter-blocks
// of slice s all have blockIdx = s (mod 8), i.e. one XCD under round-robin
// dispatch: the slice's seg segment is fetched into that L2 once and the
// other 3 scans hit (removes the 4x-redundant ~58 MB seg re-fetch).
// Worst case (mapping assumption wrong): today's behavior, correctness
// unaffected. Body = R19/R21 single-pass sort + unroll-4 gather, 4B seg.
__global__ __launch_bounds__(512) void agg_kernel(
    const int* __restrict__ seg, const int* __restrict__ scursor,
    const ushort* __restrict__ hb, const float* __restrict__ ai,
    const float* __restrict__ aj, float* __restrict__ out)
{
    __shared__ int staged[SORT_CAP];          // 5.1 KB, (src<<6)|dlocal64
    __shared__ int sorted_src[SORT_CAP];      // 5.1 KB
    __shared__ int cnt[QUARTER_NODES];
    __shared__ int run[QUARTER_NODES];
    __shared__ int rowptr[QUARTER_NODES + 1];
    __shared__ int scnt_s;

    int b = blockIdx.x;
    int s = (b & 7) + 8 * ((b >> 3) >> 2);
    if (s >= NSLICES) return;
    int quarter = (b >> 3) & 3;
    int nbase   = (s << SLICE_SHIFT) + quarter * QUARTER_NODES;
    int total = scursor[s]; if (total > SEG_CAP) total = SEG_CAP;
    const int* sp = seg + (size_t)s * SEG_CAP;

    for (int i = threadIdx.x; i < QUARTER_NODES; i += 512) { cnt[i] = 0; run[i] = 0; }
    if (threadIdx.x == 0) scnt_s = 0;
    __syncthreads();

    // single pass: stage matching edges into LDS + histogram
    int lane = threadIdx.x & 63;
    for (int i = threadIdx.x; i < total; i += 512) {
        int e = sp[i];
        int d = e & 255;                     // dst local to slice
        bool m = (d >> 6) == quarter;
        unsigned long long mask = __ballot(m);
        if (mask) {
            int leader = (int)__ffsll((long long)mask) - 1;
            int base = 0;
            if (lane == leader)
                base = atomicAdd(&scnt_s, (int)__popcll(mask));
            base = __shfl(base, leader, 64);
            if (m) {
                int p = base + (int)__popcll(mask & ((1ull << lane) - 1ull));
                if (p < SORT_CAP) staged[p] = (((unsigned)e >> 8) << 6) | (d & 63);
                atomicAdd(&cnt[d & 63], 1);
            }
        }
    }
    __syncthreads();

    // exclusive scan of 64 bins by wave 0
    if (threadIdx.x < 64) {
        int l = threadIdx.x;
        int v = cnt[l];
        int inc = v;
        #pragma unroll
        for (int d = 1; d < 64; d <<= 1) {
            int t = __shfl_up(inc, d, 64);
            if (l >= d) inc += t;
        }
        rowptr[l] = inc - v;
        if (l == 63) rowptr[64] = inc;
    }
    __syncthreads();

    // scatter from LDS staged -> sorted order
    int scnt = scnt_s; if (scnt > SORT_CAP) scnt = SORT_CAP;
    for (int i = threadIdx.x; i < scnt; i += 512) {
        int v = staged[i];
        int lb = v & 63;
        int p = rowptr[lb] + atomicAdd(&run[lb], 1);
        if (p < SORT_CAP) sorted_src[p] = (int)((unsigned)v >> 6);
    }
    __syncthreads();

    int g    = threadIdx.x >> 3;   // 0..63 == local node
    int sub  = threadIdx.x & 7;    // 8 lanes, 8 cols each
    int head = sub >> 1;
    int node = nbase + g;
    if (node >= N_NODES) return;
    int beg = rowptr[g], end = rowptr[g + 1];
    if (end > SORT_CAP) end = SORT_CAP;
    float aiv = ai[(size_t)node * HEADS + head];
    float acc[8] = {0.f, 0.f, 0.f, 0.f, 0.f, 0.f, 0.f, 0.f};
    float den = 0.f;

    int k = beg;
    for (; k + 4 <= end; k += 4) {
        int s0 = sorted_src[k + 0];
        int s1 = sorted_src[k + 1];
        int s2 = sorted_src[k + 2];
        int s3 = sorted_src[k + 3];
        float aj0 = aj[(size_t)s0 * HEADS + head];
        float aj1 = aj[(size_t)s1 * HEADS + head];
        float aj2 = aj[(size_t)s2 * HEADS + head];
        float aj3 = aj[(size_t)s3 * HEADS + head];
        short8 h0 = *(const short8*)(hb + (size_t)s0 * OUT_ALL + sub * 8);
        short8 h1 = *(const short8*)(hb + (size_t)s1 * OUT_ALL + sub * 8);
        short8 h2 = *(const short8*)(hb + (size_t)s2 * OUT_ALL + sub * 8);
        short8 h3 = *(const short8*)(hb + (size_t)s3 * OUT_ALL + sub * 8);
        float e0 = __expf(lrelu(aiv + aj0));
        float e1 = __expf(lrelu(aiv + aj1));
        float e2 = __expf(lrelu(aiv + aj2));
        float e3 = __expf(lrelu(aiv + aj3));
        den += (e0 + e1) + (e2 + e3);
        #pragma unroll
        for (int q = 0; q < 8; ++q)
            acc[q] += e0 * bf2f((ushort)h0[q]) + e1 * bf2f((ushort)h1[q]) +
                      e2 * bf2f((ushort)h2[q]) + e3 * bf2f((ushort)h3[q]);
    }
    for (; k < end; ++k) {
        int src = sorted_src[k];
        float ex = __expf(lrelu(aiv + aj[(size_t)src * HEADS + head]));
        den += ex;
        short8 hv = *(const short8*)(hb + (size_t)src * OUT_ALL + sub * 8);
        #pragma unroll
        for (int q = 0; q < 8; ++q)
            acc[q] += ex * bf2f((ushort)hv[q]);
    }

    float inv = 1.0f / (den + 1e-16f);
    float4 o0 = {acc[0] * inv, acc[1] * inv, acc[2] * inv, acc[3] * inv};
    float4 o1 = {acc[4] * inv, acc[5] * inv, acc[6] * inv, acc[7] * inv};
    float* op = out + (size_t)node * OUT_ALL + sub * 8;
    *(float4*)op = o0;
    *(float4*)(op + 4) = o1;
}

extern "C" void kernel_launch(void* const* d_in, const int* in_sizes, int n_in,
                              void* d_out, int out_size, void* d_ws, size_t ws_size,
                              hipStream_t stream) {
    const float* x     = (const float*)d_in[0];
    const int*   ei    = (const int*)d_in[1];
    const float* W     = (const float*)d_in[2];
    const float* att_i = (const float*)d_in[3];
    const float* att_j = (const float*)d_in[4];
    float* out = (float*)d_out;

    char* ws = (char*)d_ws;
    size_t off = 0;
    auto alloc = [&](size_t bytes) {
        void* p = ws + off;
        off += (bytes + 255) & ~(size_t)255;
        return p;
    };
    ushort* hb      = (ushort*)alloc((size_t)N_NODES * OUT_ALL * 2);   // 12.8 MB
    float*  ai      = (float*)alloc((size_t)N_NODES * HEADS * 4);      // 1.6 MB
    float*  aj      = (float*)alloc((size_t)N_NODES * HEADS * 4);      // 1.6 MB
    float*  wiwj    = (float*)alloc((size_t)IN_F * 8 * 4);             // 4 KB
    int*    scursor = (int*)alloc((size_t)NSLICES * 4);                // 1.6 KB
    int*    seg     = (int*)alloc((size_t)NSLICES * SEG_CAP * 4);      // 7.2 MB

    prep_kernel<<<(IN_F * 8 + 255) / 256, 256, 0, stream>>>(
        W, att_i, att_j, wiwj, scursor);
    proj_bin_kernel<<<TOTAL_BLOCKS, 256, 0, stream>>>(
        x, W, wiwj, ei, hb, ai, aj, scursor, seg);
    agg_kernel<<<AGG_GRID, 512, 0, stream>>>(seg, scursor, hb, ai, aj, out);
}